// Round 5
// baseline (39.648 us; speedup 1.0000x reference)
//
#include <hip/hip_runtime.h>

#define Bn 512
#define BC 32   // b rows per block
#define JT 32   // j columns per block

// sigmoid((sk - sj)/tau) = 1 / (1 + exp2(tj - tk)), t = s * log2(e)/tau
__device__ __forceinline__ float sigterm(float tj, float tk) {
    float e = __builtin_amdgcn_exp2f(tj - tk);
    return __builtin_amdgcn_rcpf(1.0f + e);
}

__global__ __launch_bounds__(1024, 4) void srap_main(
        const float* __restrict__ scores,
        const float* __restrict__ target,
        float* __restrict__ wsC,
        float* __restrict__ wsT) {
    // scores chunk transposed+packed+swizzled:
    // granule g(k4,b) = k4*32 + (b ^ (k4&31)) holds scores[b0+b][4k4..4k4+3]*C
    __shared__ __align__(16) float sT[(Bn / 4) * BC * 4];   // 64 KB
    __shared__ float partC[16 * BC], partT[16 * BC];

    const int tid = threadIdx.x;
    const int b0 = blockIdx.x * BC;
    const int j0 = blockIdx.y * JT;
    const int jl = tid >> 5;      // local j (0..31)
    const int bl = tid & 31;      // local b (0..31)

    const float C = 144.26950408889634f;  // log2(e)/tau, tau = 0.01

    // ---- stage scores[b0..b0+31][0..511]*C -> sT (transposed, swizzled) ----
    {
        // here jl plays the role of the staged b-row, bl the low k4 bits
        const float4* g4 = (const float4*)(scores + (size_t)(b0 + jl) * Bn);
        #pragma unroll
        for (int i = 0; i < 4; ++i) {
            const int k4 = bl + i * 32;
            float4 v = g4[k4];
            v.x *= C; v.y *= C; v.z *= C; v.w *= C;
            const int g = k4 * BC + (jl ^ (k4 & 31));
            *(float4*)(&sT[g * 4]) = v;
        }
    }
    __syncthreads();

    const int j = j0 + jl;
    const float tj = scores[(size_t)(b0 + bl) * Bn + j] * C;  // same mul as staged
    const float4* __restrict__ trow = (const float4*)(target + (size_t)j * Bn);

    float A = 0.0f;  // sum_k sigmoid
    float P = 0.0f;  // sum_k sigmoid * target[j,k]

    #pragma unroll 4
    for (int k4 = 0; k4 < Bn / 4; ++k4) {
        const float4 w = trow[k4];            // 2 distinct addrs/wave, L1/L2 hit
        const int g = k4 * BC + (bl ^ (k4 & 31));
        const float4 tk = *(const float4*)(&sT[g * 4]);

        float s0 = sigterm(tj, tk.x);
        float s1 = sigterm(tj, tk.y);
        float s2 = sigterm(tj, tk.z);
        float s3 = sigterm(tj, tk.w);
        A += (s0 + s1) + (s2 + s3);
        P = fmaf(s0, w.x, P);
        P = fmaf(s1, w.y, P);
        P = fmaf(s2, w.z, P);
        P = fmaf(s3, w.w, P);
    }

    // diag k=j contributes exactly 0.5 to both A and P (tgt[j,j]=1):
    // sim_all = A + 0.5;  pos = P - 0.5 + target[b,j]
    const float tbj = target[(size_t)(b0 + bl) * Bn + j];
    const float c = (P - 0.5f + tbj) * tbj / (A + 0.5f);

    // combine the 2 j's held by this wave (lane+32 = same b, j+1)
    float c2 = c + __shfl_down(c, 32);
    float t2 = tbj + __shfl_down(tbj, 32);
    const int wave = tid >> 6;
    if ((tid & 63) < 32) { partC[wave * 32 + bl] = c2; partT[wave * 32 + bl] = t2; }
    __syncthreads();

    if (tid < BC) {
        float cs = 0.0f, ts = 0.0f;
        #pragma unroll
        for (int w = 0; w < 16; ++w) { cs += partC[w * 32 + tid]; ts += partT[w * 32 + tid]; }
        wsC[(size_t)blockIdx.y * Bn + b0 + tid] = cs;
        wsT[(size_t)blockIdx.y * Bn + b0 + tid] = ts;
    }
}

__global__ __launch_bounds__(512) void srap_final(
        const float* __restrict__ wsC, const float* __restrict__ wsT,
        float* __restrict__ out) {
    __shared__ float red[8];
    const int b = threadIdx.x;  // 512 threads, one per batch row
    float num = 0.0f, den = 0.0f;
    #pragma unroll
    for (int jt = 0; jt < Bn / JT; ++jt) {
        num += wsC[jt * Bn + b];
        den += wsT[jt * Bn + b];
    }
    float apb = num / den;
    for (int off = 32; off; off >>= 1) apb += __shfl_down(apb, off);
    if ((b & 63) == 0) red[b >> 6] = apb;
    __syncthreads();
    if (b == 0) {
        float s = 0.0f;
        #pragma unroll
        for (int w = 0; w < 8; ++w) s += red[w];
        out[0] = 1.0f - s * (1.0f / Bn);
    }
}

extern "C" void kernel_launch(void* const* d_in, const int* in_sizes, int n_in,
                              void* d_out, int out_size, void* d_ws, size_t ws_size,
                              hipStream_t stream) {
    const float* scores = (const float*)d_in[0];
    const float* target = (const float*)d_in[1];
    float* out = (float*)d_out;
    float* wsC = (float*)d_ws;                       // 16*512 floats
    float* wsT = wsC + (Bn / JT) * Bn;               // 16*512 floats

    srap_main<<<dim3(Bn / BC, Bn / JT), dim3(1024), 0, stream>>>(scores, target, wsC, wsT);
    srap_final<<<dim3(1), dim3(512), 0, stream>>>(wsC, wsT, out);
}

// Round 6
// 39.267 us; speedup vs baseline: 1.0097x; 1.0097x over previous
//
#include <hip/hip_runtime.h>

#define Bn 512
#define BC 32   // b rows per block
#define JT 32   // j columns per block

// sigmoid((sk - sj)/tau) = 1 / (1 + exp2(tj - tk)), t = s * log2(e)/tau
__device__ __forceinline__ float sigterm(float tj, float tk) {
    float e = __builtin_amdgcn_exp2f(tj - tk);
    return __builtin_amdgcn_rcpf(1.0f + e);
}

__global__ __launch_bounds__(1024, 4) void srap_main(
        const float* __restrict__ scores,
        const float* __restrict__ target,
        float* __restrict__ wsC,
        float* __restrict__ wsT) {
    // scores chunk transposed+packed+swizzled:
    // granule g(k4,b) = k4*32 + (b ^ (k4&31)) holds scores[b0+b][4k4..4k4+3]*C
    __shared__ __align__(16) float sT[(Bn / 4) * BC * 4];   // 64 KB
    __shared__ float partC[16 * BC], partT[16 * BC];

    const int tid = threadIdx.x;
    const int b0 = blockIdx.x * BC;
    const int j0 = blockIdx.y * JT;
    const int jl = tid >> 5;      // local j (0..31)
    const int bl = tid & 31;      // local b (0..31)

    const float C = 144.26950408889634f;  // log2(e)/tau, tau = 0.01

    // ---- stage scores[b0..b0+31][0..511]*C -> sT (transposed, swizzled) ----
    {
        // here jl plays the role of the staged b-row, bl the low k4 bits
        const float4* g4 = (const float4*)(scores + (size_t)(b0 + jl) * Bn);
        #pragma unroll
        for (int i = 0; i < 4; ++i) {
            const int k4 = bl + i * 32;
            float4 v = g4[k4];
            v.x *= C; v.y *= C; v.z *= C; v.w *= C;
            const int g = k4 * BC + (jl ^ (k4 & 31));
            *(float4*)(&sT[g * 4]) = v;
        }
    }
    __syncthreads();

    const int j = j0 + jl;
    const float tj = scores[(size_t)(b0 + bl) * Bn + j] * C;  // same mul as staged
    const float4* __restrict__ trow = (const float4*)(target + (size_t)j * Bn);

    float A = 0.0f;  // sum_k sigmoid
    float P = 0.0f;  // sum_k sigmoid * target[j,k]

    #pragma unroll 4
    for (int k4 = 0; k4 < Bn / 4; ++k4) {
        const float4 w = trow[k4];            // 2 distinct addrs/wave, L1/L2 hit
        const int g = k4 * BC + (bl ^ (k4 & 31));
        const float4 tk = *(const float4*)(&sT[g * 4]);

        float s0 = sigterm(tj, tk.x);
        float s1 = sigterm(tj, tk.y);
        float s2 = sigterm(tj, tk.z);
        float s3 = sigterm(tj, tk.w);
        A += (s0 + s1) + (s2 + s3);
        P = fmaf(s0, w.x, P);
        P = fmaf(s1, w.y, P);
        P = fmaf(s2, w.z, P);
        P = fmaf(s3, w.w, P);
    }

    // diag k=j contributes exactly 0.5 to both A and P (tgt[j,j]=1):
    // sim_all = A + 0.5;  pos = P - 0.5 + target[b,j]
    const float tbj = target[(size_t)(b0 + bl) * Bn + j];
    const float c = (P - 0.5f + tbj) * tbj / (A + 0.5f);

    // combine the 2 j's held by this wave (lane+32 = same b, j+1)
    float c2 = c + __shfl_down(c, 32);
    float t2 = tbj + __shfl_down(tbj, 32);
    const int wave = tid >> 6;
    if ((tid & 63) < 32) { partC[wave * 32 + bl] = c2; partT[wave * 32 + bl] = t2; }
    __syncthreads();

    if (tid < BC) {
        float cs = 0.0f, ts = 0.0f;
        #pragma unroll
        for (int w = 0; w < 16; ++w) { cs += partC[w * 32 + tid]; ts += partT[w * 32 + tid]; }
        wsC[(size_t)blockIdx.y * Bn + b0 + tid] = cs;
        wsT[(size_t)blockIdx.y * Bn + b0 + tid] = ts;
    }
}

__global__ __launch_bounds__(512) void srap_final(
        const float* __restrict__ wsC, const float* __restrict__ wsT,
        float* __restrict__ out) {
    __shared__ float red[8];
    const int b = threadIdx.x;  // 512 threads, one per batch row
    float num = 0.0f, den = 0.0f;
    #pragma unroll
    for (int jt = 0; jt < Bn / JT; ++jt) {
        num += wsC[jt * Bn + b];
        den += wsT[jt * Bn + b];
    }
    float apb = num / den;
    for (int off = 32; off; off >>= 1) apb += __shfl_down(apb, off);
    if ((b & 63) == 0) red[b >> 6] = apb;
    __syncthreads();
    if (b == 0) {
        float s = 0.0f;
        #pragma unroll
        for (int w = 0; w < 8; ++w) s += red[w];
        out[0] = 1.0f - s * (1.0f / Bn);
    }
}

extern "C" void kernel_launch(void* const* d_in, const int* in_sizes, int n_in,
                              void* d_out, int out_size, void* d_ws, size_t ws_size,
                              hipStream_t stream) {
    const float* scores = (const float*)d_in[0];
    const float* target = (const float*)d_in[1];
    float* out = (float*)d_out;
    float* wsC = (float*)d_ws;                       // 16*512 floats
    float* wsT = wsC + (Bn / JT) * Bn;               // 16*512 floats

    srap_main<<<dim3(Bn / BC, Bn / JT), dim3(1024), 0, stream>>>(scores, target, wsC, wsT);
    srap_final<<<dim3(1), dim3(512), 0, stream>>>(wsC, wsT, out);
}